// Round 14
// baseline (108.014 us; speedup 1.0000x reference)
//
#include <hip/hip_runtime.h>
#include <hip/hip_bf16.h>
#include <math.h>
#include <stdint.h>

typedef unsigned short u16;
typedef __attribute__((ext_vector_type(8))) short bf16x8;
typedef __attribute__((ext_vector_type(4))) float f32x4;

#define MFMA16(A,B,C) __builtin_amdgcn_mfma_f32_16x16x32_bf16(A,B,C,0,0,0)
#define EXP2F(x) __builtin_amdgcn_exp2f(x)

#define BB 2
#define SS 2048
#define NT (BB*SS)

__device__ __forceinline__ u16 f2bf(float f) {
    union { float f; unsigned u; } c; c.f = f;
    unsigned r = c.u + 0x7FFF + ((c.u >> 16) & 1);
    return (u16)(r >> 16);
}
__device__ __forceinline__ float bf2f(u16 v) {
    union { unsigned u; float f; } c; c.u = ((unsigned)v) << 16;
    return c.f;
}

// async global->LDS, 16B per lane. LDS dest = wave-uniform base + lane*16B.
__device__ __forceinline__ void gl_lds16(const u16* g, u16* l) {
    __builtin_amdgcn_global_load_lds(
        (const __attribute__((address_space(1))) void*)(uintptr_t)g,
        (__attribute__((address_space(3))) void*)(uintptr_t)l, 16, 0, 0);
}

// ---------------- fp32 -> bf16 elementwise cast
__global__ __launch_bounds__(256) void cast_bf16(const float* __restrict__ in,
                                                 u16* __restrict__ out, int n) {
    int i = (blockIdx.x * 256 + threadIdx.x) * 4;
    if (i < n) {
        float4 v = *(const float4*)&in[i];
        ushort4 o;
        o.x = f2bf(v.x); o.y = f2bf(v.y); o.z = f2bf(v.z); o.w = f2bf(v.w);
        *(ushort4*)&out[i] = o;
    }
}

// ---------------- both weight transposes in one launch
__global__ __launch_bounds__(256) void transpose_weights(const float* __restrict__ wa,
                                                         const float* __restrict__ wp,
                                                         u16* __restrict__ waT,
                                                         u16* __restrict__ wpT) {
    __shared__ float tile[64][65];
    const int k0 = blockIdx.x * 64;
    const bool isA = blockIdx.y < 48;
    const int m0 = (isA ? blockIdx.y : blockIdx.y - 48) * 64;
    const int M = isA ? 3072 : 1024;
    const float* in = isA ? wa : wp;
    u16* out = isA ? waT : wpT;
    const int t = threadIdx.x;
    #pragma unroll
    for (int rep = 0; rep < 16; ++rep) {
        int idx = rep * 256 + t;
        int kk = idx >> 6, mm = idx & 63;
        tile[kk][mm] = in[(size_t)(k0 + kk) * M + m0 + mm];
    }
    __syncthreads();
    #pragma unroll
    for (int rep = 0; rep < 16; ++rep) {
        int idx = rep * 256 + t;
        int mm = idx >> 6, kk = idx & 63;
        out[(size_t)(m0 + mm) * 1024 + k0 + kk] = f2bf(tile[kk][mm]);
    }
}

// ---------------- bf16 MFMA GEMM, gl_lds staging + 2-phase double-buffer
template<int MD, typename OutT, bool FUSE_V>
__global__ __launch_bounds__(256) void gemm_bt(const u16* __restrict__ A,
                                               const u16* __restrict__ BT,
                                               const float* __restrict__ bias,
                                               OutT* __restrict__ C,
                                               u16* __restrict__ vtg) {
    __shared__ u16 As[2][128 * 32];
    __shared__ u16 Bs[2][128 * 32];
    const int n0 = blockIdx.x * 128;
    const int m0 = blockIdx.y * 128;
    const int t = threadIdx.x;
    const int lane = t & 63;
    const int w = t >> 6;
    const int wr = (w >> 1) * 64, wc = (w & 1) * 64;
    const int ln = lane & 15, hi = lane >> 4;

    f32x4 acc[4][4];
    const f32x4 fz = {0.f, 0.f, 0.f, 0.f};
    #pragma unroll
    for (int i = 0; i < 4; ++i)
        #pragma unroll
        for (int j = 0; j < 4; ++j) acc[i][j] = fz;

    const int srow_in = lane >> 2;
    const int schunk  = lane & 3;

    // prologue: stage K-tile 0 into buffer 0
    #pragma unroll
    for (int p = 0; p < 2; ++p) {
        int q   = w * 2 + p;
        int row = q * 16 + srow_in;
        int cg  = schunk ^ ((row >> 1) & 3);
        gl_lds16(&A [(size_t)(n0 + row) * 1024 + cg * 8], &As[0][q * 512]);
        gl_lds16(&BT[(size_t)(m0 + row) * 1024 + cg * 8], &Bs[0][q * 512]);
    }

    for (int i = 0; i < 32; ++i) {
        const int cur = i & 1;
        __syncthreads();

        if (i < 31) {
            const int nxt = cur ^ 1;
            const int k0 = (i + 1) * 32;
            #pragma unroll
            for (int p = 0; p < 2; ++p) {
                int q   = w * 2 + p;
                int row = q * 16 + srow_in;
                int cg  = schunk ^ ((row >> 1) & 3);
                gl_lds16(&A [(size_t)(n0 + row) * 1024 + k0 + cg * 8], &As[nxt][q * 512]);
                gl_lds16(&BT[(size_t)(m0 + row) * 1024 + k0 + cg * 8], &Bs[nxt][q * 512]);
            }
        }

        bf16x8 af[4], bf[4];
        #pragma unroll
        for (int mi = 0; mi < 4; ++mi) {
            int r = wr + mi * 16 + ln;
            af[mi] = *(const bf16x8*)&As[cur][r * 32 + ((hi ^ ((r >> 1) & 3)) << 3)];
        }
        #pragma unroll
        for (int ni = 0; ni < 4; ++ni) {
            int r = wc + ni * 16 + ln;
            bf[ni] = *(const bf16x8*)&Bs[cur][r * 32 + ((hi ^ ((r >> 1) & 3)) << 3)];
        }
        __builtin_amdgcn_s_setprio(1);
        #pragma unroll
        for (int mi = 0; mi < 4; ++mi)
            #pragma unroll
            for (int ni = 0; ni < 4; ++ni)
                acc[mi][ni] = MFMA16(af[mi], bf[ni], acc[mi][ni]);
        __builtin_amdgcn_s_setprio(0);
    }

    #pragma unroll
    for (int mi = 0; mi < 4; ++mi) {
        #pragma unroll
        for (int ni = 0; ni < 4; ++ni) {
            int col = m0 + wc + ni * 16 + ln;
            float bv = bias[col];
            int row0 = n0 + wr + mi * 16 + hi * 4;
            if (FUSE_V && col >= 2048) {
                int b  = row0 >> 11;
                int s  = row0 & 2047;
                int kt = s >> 6, kl = s & 63;
                int h  = (col - 2048) >> 6, d = (col - 2048) & 63;
                int g    = (kl >> 5) * 4 + ((kl >> 2) & 3);
                int half = (kl >> 4) & 1;
                ushort4 ov;
                ov.x = f2bf(acc[mi][ni][0] + bv);
                ov.y = f2bf(acc[mi][ni][1] + bv);
                ov.z = f2bf(acc[mi][ni][2] + bv);
                ov.w = f2bf(acc[mi][ni][3] + bv);
                *(ushort4*)&vtg[(size_t)((b * 16 + h) * 32 + kt) * 4096 +
                                (size_t)(g * 64 + d) * 8 + half * 4] = ov;
            } else {
                #pragma unroll
                for (int r = 0; r < 4; ++r) {
                    float v = acc[mi][ni][r] + bv;
                    if constexpr (sizeof(OutT) == 4) C[(size_t)(row0 + r) * MD + col] = v;
                    else                             C[(size_t)(row0 + r) * MD + col] = (OutT)f2bf(v);
                }
            }
        }
    }
}

// ---------------- attention chain state (per q-tile owned by this wave)
struct Chain {
    float m_run, l_run;
    f32x4 o[4];
    bf16x8 qb[2];
    int qrow;
};

// QK^T for one chain: saccOut[s] over 4 key sub-tiles (all indices static).
__device__ __forceinline__ void qk_step(const u16* __restrict__ KsC,
                                        const Chain& ch, f32x4 (&sacc)[4],
                                        int hi, int ln) {
    const f32x4 fz = {0.f, 0.f, 0.f, 0.f};
    __builtin_amdgcn_s_setprio(1);
    #pragma unroll
    for (int s = 0; s < 4; ++s) {
        int key = s * 16 + ln;
        f32x4 a = fz;
        #pragma unroll
        for (int t2 = 0; t2 < 2; ++t2) {
            bf16x8 kf = *(const bf16x8*)&KsC[key * 64 + (((t2 * 4 + hi) ^ (key & 7)) << 3)];
            a = MFMA16(kf, ch.qb[t2], a);
        }
        sacc[s] = a;
    }
    __builtin_amdgcn_s_setprio(0);
}

// softmax + P-pack + PV for one chain (exp2 domain, defer-max THR=8).
__device__ __forceinline__ void sm_pv_step(const u16* __restrict__ VsC,
                                           Chain& ch, f32x4 (&sacc)[4],
                                           int kt, bool diag, int hi, int ln) {
    float p_[16];
    float mloc = -1e30f;
    if (diag) {
        #pragma unroll
        for (int s = 0; s < 4; ++s)
            #pragma unroll
            for (int r = 0; r < 4; ++r) {
                int keyg = kt * 64 + s * 16 + hi * 4 + r;
                float v = (keyg <= ch.qrow) ? sacc[s][r] : -1e30f;
                p_[s * 4 + r] = v;
                mloc = fmaxf(mloc, v);
            }
    } else {
        #pragma unroll
        for (int s = 0; s < 4; ++s)
            #pragma unroll
            for (int r = 0; r < 4; ++r) {
                float v = sacc[s][r];
                p_[s * 4 + r] = v;
                mloc = fmaxf(mloc, v);
            }
    }
    mloc = fmaxf(mloc, __shfl_xor(mloc, 16));
    mloc = fmaxf(mloc, __shfl_xor(mloc, 32));
    if (!__all(mloc - ch.m_run <= 8.f)) {
        float m_new = fmaxf(ch.m_run, mloc);
        float alpha = EXP2F(ch.m_run - m_new);
        ch.l_run *= alpha;
        #pragma unroll
        for (int dt = 0; dt < 4; ++dt) ch.o[dt] *= alpha;
        ch.m_run = m_new;
    }
    float lsum = 0.f;
    #pragma unroll
    for (int i = 0; i < 16; ++i) {
        float e = EXP2F(p_[i] - ch.m_run);
        p_[i] = e;
        lsum += e;
    }
    lsum += __shfl_xor(lsum, 16);
    lsum += __shfl_xor(lsum, 32);
    ch.l_run += lsum;

    bf16x8 pa[2];
    #pragma unroll
    for (int k2 = 0; k2 < 2; ++k2) {
        union { unsigned wd[4]; bf16x8 v; } pu;
        #pragma unroll
        for (int qi = 0; qi < 4; ++qi)
            asm("v_cvt_pk_bf16_f32 %0, %1, %2"
                : "=v"(pu.wd[qi])
                : "v"(p_[k2 * 8 + 2 * qi]), "v"(p_[k2 * 8 + 2 * qi + 1]));
        pa[k2] = pu.v;
    }

    __builtin_amdgcn_s_setprio(1);
    #pragma unroll
    for (int dt = 0; dt < 4; ++dt)
        #pragma unroll
        for (int k2 = 0; k2 < 2; ++k2) {
            bf16x8 va = *(const bf16x8*)&VsC[(size_t)((k2 * 4 + hi) * 64 + dt * 16 + ln) * 8];
            ch.o[dt] = MFMA16(va, pa[k2], ch.o[dt]);
        }
    __builtin_amdgcn_s_setprio(0);
}

// ---------------- MFMA flash attention, balanced q-tile PAIR per block
// Block owns q-tiles {qtA = pair, qtB = 31-pair}: exactly 33 tile-units each.
// For kt <= qtA both chains consume the SAME staged K/V tile (two independent
// dependency chains in one basic block -> ILP); beyond that only chain B.
__global__ __launch_bounds__(256) void attn_mfma(const u16* __restrict__ qkv,
                                                 const u16* __restrict__ vtg,
                                                 u16* __restrict__ ctx) {
    __shared__ u16 Ks[2][64 * 64];  // [key][8B chunk c], c holds global c^(key&7)
    __shared__ u16 Vs[2][64 * 64];  // blocked: 16B block (g,d) at (g*64+d)*8
    const int bh = blockIdx.x;
    const int pair = blockIdx.y;             // 0..15
    const int qtA = pair, qtB = 31 - pair;
    const int b = bh >> 4, h = bh & 15;
    const int t = threadIdx.x, w = t >> 6, lane = t & 63;
    const int ln = lane & 15, hi = lane >> 4;
    const size_t tok = (size_t)b * SS;

    const f32x4 fz = {0.f, 0.f, 0.f, 0.f};
    Chain A, B;
    A.qrow = qtA * 64 + w * 16 + ln;
    B.qrow = qtB * 64 + w * 16 + ln;
    A.m_run = B.m_run = -1e30f;
    A.l_run = B.l_run = 0.f;
    #pragma unroll
    for (int i = 0; i < 4; ++i) { A.o[i] = fz; B.o[i] = fz; }

    // Q fragments (B operand of S^T), exp2 domain: scale = 0.125 * log2(e)
    #pragma unroll
    for (int t2 = 0; t2 < 2; ++t2) {
        bf16x8 va = *(const bf16x8*)&qkv[(tok + A.qrow) * 3072 + h * 64 + t2 * 32 + hi * 8];
        bf16x8 vb = *(const bf16x8*)&qkv[(tok + B.qrow) * 3072 + h * 64 + t2 * 32 + hi * 8];
        #pragma unroll
        for (int i = 0; i < 8; ++i) {
            va[i] = (short)f2bf(bf2f((u16)va[i]) * 0.180336881f);
            vb[i] = (short)f2bf(bf2f((u16)vb[i]) * 0.180336881f);
        }
        A.qb[t2] = va; B.qb[t2] = vb;
    }

    // staging lane maps
    const int kkey_l = w * 8 + (lane >> 3);   // K row, + p*32
    const int ksch   = lane & 7;              // K 16B chunk
    const u16* vsrc  = vtg + ((size_t)bh * 32) * 4096;

    // prologue: stage tile 0 into buffer 0
    {
        const size_t kvb = tok * 3072 + h * 64;
        #pragma unroll
        for (int p = 0; p < 2; ++p) {
            int kk = p * 32 + kkey_l;
            gl_lds16(&qkv[kvb + (size_t)kk * 3072 + 1024 + ((ksch ^ (kk & 7)) << 3)],
                     &Ks[0][(p * 32 + w * 8) * 64]);
            gl_lds16(&vsrc[(size_t)((w * 2 + p) * 64 + lane) * 8],
                     &Vs[0][(w * 2 + p) * 512]);
        }
    }

    for (int kt = 0; kt <= qtB; ++kt) {
        const int cur = kt & 1;
        __syncthreads();   // drains buf[cur] DMA + syncs readers

        if (kt < qtB) {    // prefetch next tile into the other buffer
            const int nxt = cur ^ 1;
            const size_t kvb = (tok + (kt + 1) * 64) * 3072 + h * 64;
            const u16* vs2 = vsrc + (size_t)(kt + 1) * 4096;
            #pragma unroll
            for (int p = 0; p < 2; ++p) {
                int kk = p * 32 + kkey_l;
                gl_lds16(&qkv[kvb + (size_t)kk * 3072 + 1024 + ((ksch ^ (kk & 7)) << 3)],
                         &Ks[nxt][(p * 32 + w * 8) * 64]);
                gl_lds16(&vs2[(size_t)((w * 2 + p) * 64 + lane) * 8],
                         &Vs[nxt][(w * 2 + p) * 512]);
            }
        }

        const u16* KsC = &Ks[cur][0];
        const u16* VsC = &Vs[cur][0];
        if (kt <= qtA) {
            // both chains on the same staged tile: back-to-back in one BB
            f32x4 sb[4], sa[4];
            qk_step(KsC, B, sb, hi, ln);
            qk_step(KsC, A, sa, hi, ln);
            sm_pv_step(VsC, B, sb, kt, false, hi, ln);         // qtB>15>=kt: no diag
            sm_pv_step(VsC, A, sa, kt, kt == qtA, hi, ln);
        } else {
            f32x4 sb[4];
            qk_step(KsC, B, sb, hi, ln);
            sm_pv_step(VsC, B, sb, kt, kt == qtB, hi, ln);
        }
    }

    // epilogue: both chains; lane owns qrow; d = dt*16 + hi*4 + r
    float invA = 1.f / A.l_run;
    float invB = 1.f / B.l_run;
    #pragma unroll
    for (int dt = 0; dt < 4; ++dt) {
        ushort4 oa, ob;
        oa.x = f2bf(A.o[dt][0] * invA); oa.y = f2bf(A.o[dt][1] * invA);
        oa.z = f2bf(A.o[dt][2] * invA); oa.w = f2bf(A.o[dt][3] * invA);
        ob.x = f2bf(B.o[dt][0] * invB); ob.y = f2bf(B.o[dt][1] * invB);
        ob.z = f2bf(B.o[dt][2] * invB); ob.w = f2bf(B.o[dt][3] * invB);
        *(ushort4*)&ctx[(tok + A.qrow) * 1024 + h * 64 + dt * 16 + hi * 4] = oa;
        *(ushort4*)&ctx[(tok + B.qrow) * 1024 + h * 64 + dt * 16 + hi * 4] = ob;
    }
}

extern "C" void kernel_launch(void* const* d_in, const int* in_sizes, int n_in,
                              void* d_out, int out_size, void* d_ws, size_t ws_size,
                              hipStream_t stream) {
    const float* hs     = (const float*)d_in[0];   // [2,2048,1024]
    const float* w_attn = (const float*)d_in[1];   // [1024,3072]
    const float* b_attn = (const float*)d_in[2];   // [3072]
    const float* w_proj = (const float*)d_in[3];   // [1024,1024]
    const float* b_proj = (const float*)d_in[4];   // [1024]
    float* out = (float*)d_out;                    // [2,2048,1024] fp32

    char* ws = (char*)d_ws;
    u16* hsb  = (u16*)ws;                          // 8 MB
    u16* waT  = (u16*)(ws + ((size_t)8  << 20));   // 6 MB  [3072][1024]
    u16* wpT  = (u16*)(ws + ((size_t)14 << 20));   // 2 MB  [1024][1024]
    u16* qkvb = (u16*)(ws + ((size_t)16 << 20));   // 24 MB [4096][3072] (V region unused)
    u16* ctxb = (u16*)(ws + ((size_t)40 << 20));   // 8 MB  [4096][1024]
    u16* vtg  = (u16*)(ws + ((size_t)48 << 20));   // 8 MB  blocked V^T

    cast_bf16<<<4096, 256, 0, stream>>>(hs, hsb, NT * 1024);
    transpose_weights<<<dim3(16, 64), 256, 0, stream>>>(w_attn, w_proj, waT, wpT);

    gemm_bt<3072, u16, true><<<dim3(32, 24), 256, 0, stream>>>(hsb, waT, b_attn, qkvb, vtg);
    attn_mfma<<<dim3(BB * 16, 16), 256, 0, stream>>>(qkvb, vtg, ctxb);
    gemm_bt<1024, float, false><<<dim3(32, 8), 256, 0, stream>>>(ctxb, wpT, b_proj, out, nullptr);
}

// Round 15
// 101.379 us; speedup vs baseline: 1.0655x; 1.0655x over previous
//
#include <hip/hip_runtime.h>
#include <hip/hip_bf16.h>
#include <math.h>
#include <stdint.h>

typedef unsigned short u16;
typedef __attribute__((ext_vector_type(8))) short bf16x8;
typedef __attribute__((ext_vector_type(4))) float f32x4;

#define MFMA16(A,B,C) __builtin_amdgcn_mfma_f32_16x16x32_bf16(A,B,C,0,0,0)
#define EXP2F(x) __builtin_amdgcn_exp2f(x)

#define BB 2
#define SS 2048
#define NT (BB*SS)

__device__ __forceinline__ u16 f2bf(float f) {
    union { float f; unsigned u; } c; c.f = f;
    unsigned r = c.u + 0x7FFF + ((c.u >> 16) & 1);
    return (u16)(r >> 16);
}
__device__ __forceinline__ float bf2f(u16 v) {
    union { unsigned u; float f; } c; c.u = ((unsigned)v) << 16;
    return c.f;
}

// async global->LDS, 16B per lane. LDS dest = wave-uniform base + lane*16B.
__device__ __forceinline__ void gl_lds16(const u16* g, u16* l) {
    __builtin_amdgcn_global_load_lds(
        (const __attribute__((address_space(1))) void*)(uintptr_t)g,
        (__attribute__((address_space(3))) void*)(uintptr_t)l, 16, 0, 0);
}

// ---------------- fused prep: hs cast (blocks 0..4095) + both weight
// transposes (blocks 4096..5119). Bodies identical to the proven standalone
// kernels; branch is block-uniform.
__global__ __launch_bounds__(256) void prep(const float* __restrict__ hs,
                                            const float* __restrict__ wa,
                                            const float* __restrict__ wp,
                                            u16* __restrict__ hsb,
                                            u16* __restrict__ waT,
                                            u16* __restrict__ wpT) {
    __shared__ float tile[64][65];
    const int bid = blockIdx.x;
    const int t = threadIdx.x;
    if (bid < 4096) {
        int i = (bid * 256 + t) * 4;           // exact: 4096*256*4 = NT*1024
        float4 v = *(const float4*)&hs[i];
        ushort4 o;
        o.x = f2bf(v.x); o.y = f2bf(v.y); o.z = f2bf(v.z); o.w = f2bf(v.w);
        *(ushort4*)&hsb[i] = o;
        return;
    }
    const int r = bid - 4096;                  // 0..1023
    const int k0 = (r & 15) * 64;
    const int by = r >> 4;                     // 0..63
    const bool isA = by < 48;
    const int m0 = (isA ? by : by - 48) * 64;
    const int M = isA ? 3072 : 1024;
    const float* in = isA ? wa : wp;
    u16* out = isA ? waT : wpT;
    #pragma unroll
    for (int rep = 0; rep < 16; ++rep) {
        int idx = rep * 256 + t;
        int kk = idx >> 6, mm = idx & 63;
        tile[kk][mm] = in[(size_t)(k0 + kk) * M + m0 + mm];
    }
    __syncthreads();
    #pragma unroll
    for (int rep = 0; rep < 16; ++rep) {
        int idx = rep * 256 + t;
        int mm = idx >> 6, kk = idx & 63;
        out[(size_t)(m0 + mm) * 1024 + k0 + kk] = f2bf(tile[kk][mm]);
    }
}

// ---------------- bf16 MFMA GEMM, gl_lds staging + 2-phase double-buffer
// (round-13 proven). f(r)=(r>>1)&3 involution on 16B chunks (conflict-free).
template<int MD, typename OutT, bool FUSE_V>
__global__ __launch_bounds__(256) void gemm_bt(const u16* __restrict__ A,
                                               const u16* __restrict__ BT,
                                               const float* __restrict__ bias,
                                               OutT* __restrict__ C,
                                               u16* __restrict__ vtg) {
    __shared__ u16 As[2][128 * 32];
    __shared__ u16 Bs[2][128 * 32];
    const int n0 = blockIdx.x * 128;
    const int m0 = blockIdx.y * 128;
    const int t = threadIdx.x;
    const int lane = t & 63;
    const int w = t >> 6;
    const int wr = (w >> 1) * 64, wc = (w & 1) * 64;
    const int ln = lane & 15, hi = lane >> 4;

    f32x4 acc[4][4];
    const f32x4 fz = {0.f, 0.f, 0.f, 0.f};
    #pragma unroll
    for (int i = 0; i < 4; ++i)
        #pragma unroll
        for (int j = 0; j < 4; ++j) acc[i][j] = fz;

    const int srow_in = lane >> 2;
    const int schunk  = lane & 3;

    // prologue: stage K-tile 0 into buffer 0
    #pragma unroll
    for (int p = 0; p < 2; ++p) {
        int q   = w * 2 + p;
        int row = q * 16 + srow_in;
        int cg  = schunk ^ ((row >> 1) & 3);
        gl_lds16(&A [(size_t)(n0 + row) * 1024 + cg * 8], &As[0][q * 512]);
        gl_lds16(&BT[(size_t)(m0 + row) * 1024 + cg * 8], &Bs[0][q * 512]);
    }

    for (int i = 0; i < 32; ++i) {
        const int cur = i & 1;
        __syncthreads();

        if (i < 31) {
            const int nxt = cur ^ 1;
            const int k0 = (i + 1) * 32;
            #pragma unroll
            for (int p = 0; p < 2; ++p) {
                int q   = w * 2 + p;
                int row = q * 16 + srow_in;
                int cg  = schunk ^ ((row >> 1) & 3);
                gl_lds16(&A [(size_t)(n0 + row) * 1024 + k0 + cg * 8], &As[nxt][q * 512]);
                gl_lds16(&BT[(size_t)(m0 + row) * 1024 + k0 + cg * 8], &Bs[nxt][q * 512]);
            }
        }

        bf16x8 af[4], bf[4];
        #pragma unroll
        for (int mi = 0; mi < 4; ++mi) {
            int r = wr + mi * 16 + ln;
            af[mi] = *(const bf16x8*)&As[cur][r * 32 + ((hi ^ ((r >> 1) & 3)) << 3)];
        }
        #pragma unroll
        for (int ni = 0; ni < 4; ++ni) {
            int r = wc + ni * 16 + ln;
            bf[ni] = *(const bf16x8*)&Bs[cur][r * 32 + ((hi ^ ((r >> 1) & 3)) << 3)];
        }
        __builtin_amdgcn_s_setprio(1);
        #pragma unroll
        for (int mi = 0; mi < 4; ++mi)
            #pragma unroll
            for (int ni = 0; ni < 4; ++ni)
                acc[mi][ni] = MFMA16(af[mi], bf[ni], acc[mi][ni]);
        __builtin_amdgcn_s_setprio(0);
    }

    #pragma unroll
    for (int mi = 0; mi < 4; ++mi) {
        #pragma unroll
        for (int ni = 0; ni < 4; ++ni) {
            int col = m0 + wc + ni * 16 + ln;
            float bv = bias[col];
            int row0 = n0 + wr + mi * 16 + hi * 4;
            if (FUSE_V && col >= 2048) {
                int b  = row0 >> 11;
                int s  = row0 & 2047;
                int kt = s >> 6, kl = s & 63;
                int h  = (col - 2048) >> 6, d = (col - 2048) & 63;
                int g    = (kl >> 5) * 4 + ((kl >> 2) & 3);
                int half = (kl >> 4) & 1;
                ushort4 ov;
                ov.x = f2bf(acc[mi][ni][0] + bv);
                ov.y = f2bf(acc[mi][ni][1] + bv);
                ov.z = f2bf(acc[mi][ni][2] + bv);
                ov.w = f2bf(acc[mi][ni][3] + bv);
                *(ushort4*)&vtg[(size_t)((b * 16 + h) * 32 + kt) * 4096 +
                                (size_t)(g * 64 + d) * 8 + half * 4] = ov;
            } else {
                #pragma unroll
                for (int r = 0; r < 4; ++r) {
                    float v = acc[mi][ni][r] + bv;
                    if constexpr (sizeof(OutT) == 4) C[(size_t)(row0 + r) * MD + col] = v;
                    else                             C[(size_t)(row0 + r) * MD + col] = (OutT)f2bf(v);
                }
            }
        }
    }
}

// ---------------- MFMA flash attention (bf16), QBLK=64 — round-13 proven
__global__ __launch_bounds__(256) void attn_mfma(const u16* __restrict__ qkv,
                                                 const u16* __restrict__ vtg,
                                                 u16* __restrict__ ctx) {
    __shared__ u16 Ks[2][64 * 64];  // [key][8B chunk c], c holds global c^(key&7)
    __shared__ u16 Vs[2][64 * 64];  // blocked: 16B block (g,d) at (g*64+d)*8
    const int bh = blockIdx.x;
    const int qt = 31 - blockIdx.y;          // longest-first (LPT)
    const int b = bh >> 4, h = bh & 15;
    const int t = threadIdx.x, w = t >> 6, lane = t & 63;
    const int ln = lane & 15, hi = lane >> 4;
    const int qrow = qt * 64 + w * 16 + ln;
    const size_t tok = (size_t)b * SS;

    // Q fragment (B operand of S^T), exp2 domain: scale = 0.125 * log2(e)
    bf16x8 qb[2];
    #pragma unroll
    for (int t2 = 0; t2 < 2; ++t2) {
        bf16x8 v = *(const bf16x8*)&qkv[(tok + qrow) * 3072 + h * 64 + t2 * 32 + hi * 8];
        #pragma unroll
        for (int i = 0; i < 8; ++i)
            v[i] = (short)f2bf(bf2f((u16)v[i]) * 0.180336881f);
        qb[t2] = v;
    }

    float m_run = -1e30f, l_run = 0.f;
    f32x4 o[4];
    const f32x4 fz = {0.f, 0.f, 0.f, 0.f};
    #pragma unroll
    for (int i = 0; i < 4; ++i) o[i] = fz;

    // staging lane maps
    const int kkey_l = w * 8 + (lane >> 3);   // K row, + p*32
    const int ksch   = lane & 7;              // K 16B chunk
    const u16* vsrc  = vtg + ((size_t)bh * 32) * 4096;

    // prologue: stage tile 0 into buffer 0
    {
        const size_t kvb = tok * 3072 + h * 64;
        #pragma unroll
        for (int p = 0; p < 2; ++p) {
            int kk = p * 32 + kkey_l;
            gl_lds16(&qkv[kvb + (size_t)kk * 3072 + 1024 + ((ksch ^ (kk & 7)) << 3)],
                     &Ks[0][(p * 32 + w * 8) * 64]);
            gl_lds16(&vsrc[(size_t)((w * 2 + p) * 64 + lane) * 8],
                     &Vs[0][(w * 2 + p) * 512]);
        }
    }

    for (int kt = 0; kt <= qt; ++kt) {
        const int cur = kt & 1;
        __syncthreads();   // drains buf[cur] DMA (vmcnt0 before barrier) + syncs

        if (kt < qt) {     // issue next-tile DMA into the other buffer
            const int nxt = cur ^ 1;
            const size_t kvb = (tok + (kt + 1) * 64) * 3072 + h * 64;
            const u16* vs2 = vsrc + (size_t)(kt + 1) * 4096;
            #pragma unroll
            for (int p = 0; p < 2; ++p) {
                int kk = p * 32 + kkey_l;
                gl_lds16(&qkv[kvb + (size_t)kk * 3072 + 1024 + ((ksch ^ (kk & 7)) << 3)],
                         &Ks[nxt][(p * 32 + w * 8) * 64]);
                gl_lds16(&vs2[(size_t)((w * 2 + p) * 64 + lane) * 8],
                         &Vs[nxt][(w * 2 + p) * 512]);
            }
        }

        // S^T = K . Q^T : 4 key sub-tiles of 16
        f32x4 sacc[4];
        __builtin_amdgcn_s_setprio(1);
        #pragma unroll
        for (int s = 0; s < 4; ++s) {
            int key = s * 16 + ln;
            f32x4 a = fz;
            #pragma unroll
            for (int t2 = 0; t2 < 2; ++t2) {
                bf16x8 kf = *(const bf16x8*)&Ks[cur][key * 64 + (((t2 * 4 + hi) ^ (key & 7)) << 3)];
                a = MFMA16(kf, qb[t2], a);
            }
            sacc[s] = a;
        }
        __builtin_amdgcn_s_setprio(0);

        // online softmax, exp2 domain (lane owns one q-row; reduce over hi)
        float p_[16];
        float mloc = -1e30f;
        if (kt == qt) {
            #pragma unroll
            for (int s = 0; s < 4; ++s)
                #pragma unroll
                for (int r = 0; r < 4; ++r) {
                    int keyg = kt * 64 + s * 16 + hi * 4 + r;
                    float v = (keyg <= qrow) ? sacc[s][r] : -1e30f;
                    p_[s * 4 + r] = v;
                    mloc = fmaxf(mloc, v);
                }
        } else {
            #pragma unroll
            for (int s = 0; s < 4; ++s)
                #pragma unroll
                for (int r = 0; r < 4; ++r) {
                    float v = sacc[s][r];
                    p_[s * 4 + r] = v;
                    mloc = fmaxf(mloc, v);
                }
        }
        mloc = fmaxf(mloc, __shfl_xor(mloc, 16));
        mloc = fmaxf(mloc, __shfl_xor(mloc, 32));
        // defer-max: rescale only if some row's max grew past THR=8 (2^8 headroom)
        if (!__all(mloc - m_run <= 8.f)) {
            float m_new = fmaxf(m_run, mloc);
            float alpha = EXP2F(m_run - m_new);
            l_run *= alpha;
            #pragma unroll
            for (int dt = 0; dt < 4; ++dt) o[dt] *= alpha;
            m_run = m_new;
        }
        float lsum = 0.f;
        #pragma unroll
        for (int i = 0; i < 16; ++i) {
            float e = EXP2F(p_[i] - m_run);
            p_[i] = e;
            lsum += e;
        }
        lsum += __shfl_xor(lsum, 16);
        lsum += __shfl_xor(lsum, 32);
        l_run += lsum;

        // P -> bf16 fragments via packed convert (identity key bijection)
        bf16x8 pa[2];
        #pragma unroll
        for (int k2 = 0; k2 < 2; ++k2) {
            union { unsigned wd[4]; bf16x8 v; } pu;
            #pragma unroll
            for (int qi = 0; qi < 4; ++qi)
                asm("v_cvt_pk_bf16_f32 %0, %1, %2"
                    : "=v"(pu.wd[qi])
                    : "v"(p_[k2 * 8 + 2 * qi]), "v"(p_[k2 * 8 + 2 * qi + 1]));
            pa[k2] = pu.v;
        }

        // O^T += V^T . P^T ; blocked V: one b128 per (dt,k2)
        __builtin_amdgcn_s_setprio(1);
        #pragma unroll
        for (int dt = 0; dt < 4; ++dt)
            #pragma unroll
            for (int k2 = 0; k2 < 2; ++k2) {
                bf16x8 va = *(const bf16x8*)&Vs[cur][(size_t)((k2 * 4 + hi) * 64 + dt * 16 + ln) * 8];
                o[dt] = MFMA16(va, pa[k2], o[dt]);
            }
        __builtin_amdgcn_s_setprio(0);
    }

    // epilogue: lane owns qrow; d = dt*16 + hi*4 + r
    float inv = 1.f / l_run;
    #pragma unroll
    for (int dt = 0; dt < 4; ++dt) {
        ushort4 ov;
        ov.x = f2bf(o[dt][0] * inv);
        ov.y = f2bf(o[dt][1] * inv);
        ov.z = f2bf(o[dt][2] * inv);
        ov.w = f2bf(o[dt][3] * inv);
        *(ushort4*)&ctx[(tok + qrow) * 1024 + h * 64 + dt * 16 + hi * 4] = ov;
    }
}

extern "C" void kernel_launch(void* const* d_in, const int* in_sizes, int n_in,
                              void* d_out, int out_size, void* d_ws, size_t ws_size,
                              hipStream_t stream) {
    const float* hs     = (const float*)d_in[0];   // [2,2048,1024]
    const float* w_attn = (const float*)d_in[1];   // [1024,3072]
    const float* b_attn = (const float*)d_in[2];   // [3072]
    const float* w_proj = (const float*)d_in[3];   // [1024,1024]
    const float* b_proj = (const float*)d_in[4];   // [1024]
    float* out = (float*)d_out;                    // [2,2048,1024] fp32

    char* ws = (char*)d_ws;
    u16* hsb  = (u16*)ws;                          // 8 MB
    u16* waT  = (u16*)(ws + ((size_t)8  << 20));   // 6 MB  [3072][1024]
    u16* wpT  = (u16*)(ws + ((size_t)14 << 20));   // 2 MB  [1024][1024]
    u16* qkvb = (u16*)(ws + ((size_t)16 << 20));   // 24 MB [4096][3072] (V region unused)
    u16* ctxb = (u16*)(ws + ((size_t)40 << 20));   // 8 MB  [4096][1024]
    u16* vtg  = (u16*)(ws + ((size_t)48 << 20));   // 8 MB  blocked V^T

    prep<<<5120, 256, 0, stream>>>(hs, w_attn, w_proj, hsb, waT, wpT);

    gemm_bt<3072, u16, true><<<dim3(32, 24), 256, 0, stream>>>(hsb, waT, b_attn, qkvb, vtg);
    attn_mfma<<<dim3(BB * 16, SS / 64), 256, 0, stream>>>(qkvb, vtg, ctxb);
    gemm_bt<1024, float, false><<<dim3(32, 8), 256, 0, stream>>>(ctxb, wpT, b_proj, out, nullptr);
}

// Round 16
// 95.861 us; speedup vs baseline: 1.1268x; 1.0576x over previous
//
#include <hip/hip_runtime.h>
#include <hip/hip_bf16.h>
#include <math.h>
#include <stdint.h>

typedef unsigned short u16;
typedef __attribute__((ext_vector_type(8))) short bf16x8;
typedef __attribute__((ext_vector_type(4))) float f32x4;

#define MFMA16(A,B,C) __builtin_amdgcn_mfma_f32_16x16x32_bf16(A,B,C,0,0,0)
#define EXP2F(x) __builtin_amdgcn_exp2f(x)

#define BB 2
#define SS 2048
#define NT (BB*SS)

__device__ __forceinline__ u16 f2bf(float f) {
    union { float f; unsigned u; } c; c.f = f;
    unsigned r = c.u + 0x7FFF + ((c.u >> 16) & 1);
    return (u16)(r >> 16);
}
__device__ __forceinline__ float bf2f(u16 v) {
    union { unsigned u; float f; } c; c.u = ((unsigned)v) << 16;
    return c.f;
}

// async global->LDS, 16B per lane. LDS dest = wave-uniform base + lane*16B.
__device__ __forceinline__ void gl_lds16(const u16* g, u16* l) {
    __builtin_amdgcn_global_load_lds(
        (const __attribute__((address_space(1))) void*)(uintptr_t)g,
        (__attribute__((address_space(3))) void*)(uintptr_t)l, 16, 0, 0);
}

// ---------------- fused prep: hs cast (blocks 0..4095) + both weight
// transposes (blocks 4096..5119).
__global__ __launch_bounds__(256) void prep(const float* __restrict__ hs,
                                            const float* __restrict__ wa,
                                            const float* __restrict__ wp,
                                            u16* __restrict__ hsb,
                                            u16* __restrict__ waT,
                                            u16* __restrict__ wpT) {
    __shared__ float tile[64][65];
    const int bid = blockIdx.x;
    const int t = threadIdx.x;
    if (bid < 4096) {
        int i = (bid * 256 + t) * 4;
        float4 v = *(const float4*)&hs[i];
        ushort4 o;
        o.x = f2bf(v.x); o.y = f2bf(v.y); o.z = f2bf(v.z); o.w = f2bf(v.w);
        *(ushort4*)&hsb[i] = o;
        return;
    }
    const int r = bid - 4096;
    const int k0 = (r & 15) * 64;
    const int by = r >> 4;
    const bool isA = by < 48;
    const int m0 = (isA ? by : by - 48) * 64;
    const int M = isA ? 3072 : 1024;
    const float* in = isA ? wa : wp;
    u16* out = isA ? waT : wpT;
    #pragma unroll
    for (int rep = 0; rep < 16; ++rep) {
        int idx = rep * 256 + t;
        int kk = idx >> 6, mm = idx & 63;
        tile[kk][mm] = in[(size_t)(k0 + kk) * M + m0 + mm];
    }
    __syncthreads();
    #pragma unroll
    for (int rep = 0; rep < 16; ++rep) {
        int idx = rep * 256 + t;
        int mm = idx >> 6, kk = idx & 63;
        out[(size_t)(m0 + mm) * 1024 + k0 + kk] = f2bf(tile[kk][mm]);
    }
}

// ---------------- bf16 MFMA GEMM, gl_lds staging + 2-phase double-buffer
// (round-13 proven). f(r)=(r>>1)&3 involution on 16B chunks (conflict-free).
template<int MD, typename OutT, bool FUSE_V>
__global__ __launch_bounds__(256) void gemm_bt(const u16* __restrict__ A,
                                               const u16* __restrict__ BT,
                                               const float* __restrict__ bias,
                                               OutT* __restrict__ C,
                                               u16* __restrict__ vtg) {
    __shared__ u16 As[2][128 * 32];
    __shared__ u16 Bs[2][128 * 32];
    const int n0 = blockIdx.x * 128;
    const int m0 = blockIdx.y * 128;
    const int t = threadIdx.x;
    const int lane = t & 63;
    const int w = t >> 6;
    const int wr = (w >> 1) * 64, wc = (w & 1) * 64;
    const int ln = lane & 15, hi = lane >> 4;

    f32x4 acc[4][4];
    const f32x4 fz = {0.f, 0.f, 0.f, 0.f};
    #pragma unroll
    for (int i = 0; i < 4; ++i)
        #pragma unroll
        for (int j = 0; j < 4; ++j) acc[i][j] = fz;

    const int srow_in = lane >> 2;
    const int schunk  = lane & 3;

    #pragma unroll
    for (int p = 0; p < 2; ++p) {
        int q   = w * 2 + p;
        int row = q * 16 + srow_in;
        int cg  = schunk ^ ((row >> 1) & 3);
        gl_lds16(&A [(size_t)(n0 + row) * 1024 + cg * 8], &As[0][q * 512]);
        gl_lds16(&BT[(size_t)(m0 + row) * 1024 + cg * 8], &Bs[0][q * 512]);
    }

    for (int i = 0; i < 32; ++i) {
        const int cur = i & 1;
        __syncthreads();

        if (i < 31) {
            const int nxt = cur ^ 1;
            const int k0 = (i + 1) * 32;
            #pragma unroll
            for (int p = 0; p < 2; ++p) {
                int q   = w * 2 + p;
                int row = q * 16 + srow_in;
                int cg  = schunk ^ ((row >> 1) & 3);
                gl_lds16(&A [(size_t)(n0 + row) * 1024 + k0 + cg * 8], &As[nxt][q * 512]);
                gl_lds16(&BT[(size_t)(m0 + row) * 1024 + k0 + cg * 8], &Bs[nxt][q * 512]);
            }
        }

        bf16x8 af[4], bf[4];
        #pragma unroll
        for (int mi = 0; mi < 4; ++mi) {
            int r = wr + mi * 16 + ln;
            af[mi] = *(const bf16x8*)&As[cur][r * 32 + ((hi ^ ((r >> 1) & 3)) << 3)];
        }
        #pragma unroll
        for (int ni = 0; ni < 4; ++ni) {
            int r = wc + ni * 16 + ln;
            bf[ni] = *(const bf16x8*)&Bs[cur][r * 32 + ((hi ^ ((r >> 1) & 3)) << 3)];
        }
        __builtin_amdgcn_s_setprio(1);
        #pragma unroll
        for (int mi = 0; mi < 4; ++mi)
            #pragma unroll
            for (int ni = 0; ni < 4; ++ni)
                acc[mi][ni] = MFMA16(af[mi], bf[ni], acc[mi][ni]);
        __builtin_amdgcn_s_setprio(0);
    }

    #pragma unroll
    for (int mi = 0; mi < 4; ++mi) {
        #pragma unroll
        for (int ni = 0; ni < 4; ++ni) {
            int col = m0 + wc + ni * 16 + ln;
            float bv = bias[col];
            int row0 = n0 + wr + mi * 16 + hi * 4;
            if (FUSE_V && col >= 2048) {
                int b  = row0 >> 11;
                int s  = row0 & 2047;
                int kt = s >> 6, kl = s & 63;
                int h  = (col - 2048) >> 6, d = (col - 2048) & 63;
                int g    = (kl >> 5) * 4 + ((kl >> 2) & 3);
                int half = (kl >> 4) & 1;
                ushort4 ov;
                ov.x = f2bf(acc[mi][ni][0] + bv);
                ov.y = f2bf(acc[mi][ni][1] + bv);
                ov.z = f2bf(acc[mi][ni][2] + bv);
                ov.w = f2bf(acc[mi][ni][3] + bv);
                *(ushort4*)&vtg[(size_t)((b * 16 + h) * 32 + kt) * 4096 +
                                (size_t)(g * 64 + d) * 8 + half * 4] = ov;
            } else {
                #pragma unroll
                for (int r = 0; r < 4; ++r) {
                    float v = acc[mi][ni][r] + bv;
                    if constexpr (sizeof(OutT) == 4) C[(size_t)(row0 + r) * MD + col] = v;
                    else                             C[(size_t)(row0 + r) * MD + col] = (OutT)f2bf(v);
                }
            }
        }
    }
}

// ---------------- MFMA flash attention (bf16), QBLK=64
// r16: shuffle-free softmax steady state — per-lane partial max feeds the
// __all() defer-max ballot (64-lane ballot spans all hi-quadrants of every
// row, so it's equivalent to the row-max condition); cross-hi max shfls move
// into the rare rescale branch; l_run kept as per-lane partial, reduced once
// in the epilogue. Bit-exact vs r15 (fmax reassociation only).
__global__ __launch_bounds__(256) void attn_mfma(const u16* __restrict__ qkv,
                                                 const u16* __restrict__ vtg,
                                                 u16* __restrict__ ctx) {
    __shared__ u16 Ks[2][64 * 64];  // [key][8B chunk c], c holds global c^(key&7)
    __shared__ u16 Vs[2][64 * 64];  // blocked: 16B block (g,d) at (g*64+d)*8
    const int bh = blockIdx.x;
    const int qt = 31 - blockIdx.y;          // longest-first (LPT)
    const int b = bh >> 4, h = bh & 15;
    const int t = threadIdx.x, w = t >> 6, lane = t & 63;
    const int ln = lane & 15, hi = lane >> 4;
    const int qrow = qt * 64 + w * 16 + ln;
    const size_t tok = (size_t)b * SS;

    // Q fragment (B operand of S^T), exp2 domain: scale = 0.125 * log2(e)
    bf16x8 qb[2];
    #pragma unroll
    for (int t2 = 0; t2 < 2; ++t2) {
        bf16x8 v = *(const bf16x8*)&qkv[(tok + qrow) * 3072 + h * 64 + t2 * 32 + hi * 8];
        #pragma unroll
        for (int i = 0; i < 8; ++i)
            v[i] = (short)f2bf(bf2f((u16)v[i]) * 0.180336881f);
        qb[t2] = v;
    }

    float m_run = -1e30f;      // row-uniform (updated only in rescale branch)
    float l_run = 0.f;         // PER-LANE partial (this lane's 16 key-slots)
    f32x4 o[4];
    const f32x4 fz = {0.f, 0.f, 0.f, 0.f};
    #pragma unroll
    for (int i = 0; i < 4; ++i) o[i] = fz;

    // staging lane maps
    const int kkey_l = w * 8 + (lane >> 3);   // K row, + p*32
    const int ksch   = lane & 7;              // K 16B chunk
    const u16* vsrc  = vtg + ((size_t)bh * 32) * 4096;

    // prologue: stage tile 0 into buffer 0
    {
        const size_t kvb = tok * 3072 + h * 64;
        #pragma unroll
        for (int p = 0; p < 2; ++p) {
            int kk = p * 32 + kkey_l;
            gl_lds16(&qkv[kvb + (size_t)kk * 3072 + 1024 + ((ksch ^ (kk & 7)) << 3)],
                     &Ks[0][(p * 32 + w * 8) * 64]);
            gl_lds16(&vsrc[(size_t)((w * 2 + p) * 64 + lane) * 8],
                     &Vs[0][(w * 2 + p) * 512]);
        }
    }

    for (int kt = 0; kt <= qt; ++kt) {
        const int cur = kt & 1;
        __syncthreads();   // drains buf[cur] DMA (vmcnt0 before barrier) + syncs

        if (kt < qt) {     // issue next-tile DMA into the other buffer
            const int nxt = cur ^ 1;
            const size_t kvb = (tok + (kt + 1) * 64) * 3072 + h * 64;
            const u16* vs2 = vsrc + (size_t)(kt + 1) * 4096;
            #pragma unroll
            for (int p = 0; p < 2; ++p) {
                int kk = p * 32 + kkey_l;
                gl_lds16(&qkv[kvb + (size_t)kk * 3072 + 1024 + ((ksch ^ (kk & 7)) << 3)],
                         &Ks[nxt][(p * 32 + w * 8) * 64]);
                gl_lds16(&vs2[(size_t)((w * 2 + p) * 64 + lane) * 8],
                         &Vs[nxt][(w * 2 + p) * 512]);
            }
        }

        // S^T = K . Q^T : 4 key sub-tiles of 16
        f32x4 sacc[4];
        __builtin_amdgcn_s_setprio(1);
        #pragma unroll
        for (int s = 0; s < 4; ++s) {
            int key = s * 16 + ln;
            f32x4 a = fz;
            #pragma unroll
            for (int t2 = 0; t2 < 2; ++t2) {
                bf16x8 kf = *(const bf16x8*)&Ks[cur][key * 64 + (((t2 * 4 + hi) ^ (key & 7)) << 3)];
                a = MFMA16(kf, qb[t2], a);
            }
            sacc[s] = a;
        }
        __builtin_amdgcn_s_setprio(0);

        // mask + per-lane partial max (max3-friendly triples; no shuffles)
        float p_[16];
        if (kt == qt) {
            #pragma unroll
            for (int s = 0; s < 4; ++s)
                #pragma unroll
                for (int r = 0; r < 4; ++r) {
                    int keyg = kt * 64 + s * 16 + hi * 4 + r;
                    p_[s * 4 + r] = (keyg <= qrow) ? sacc[s][r] : -1e30f;
                }
        } else {
            #pragma unroll
            for (int s = 0; s < 4; ++s)
                #pragma unroll
                for (int r = 0; r < 4; ++r)
                    p_[s * 4 + r] = sacc[s][r];
        }
        float mp = fmaxf(fmaxf(p_[0], p_[1]), p_[2]);
        mp = fmaxf(fmaxf(mp, p_[3]),  p_[4]);
        mp = fmaxf(fmaxf(mp, p_[5]),  p_[6]);
        mp = fmaxf(fmaxf(mp, p_[7]),  p_[8]);
        mp = fmaxf(fmaxf(mp, p_[9]),  p_[10]);
        mp = fmaxf(fmaxf(mp, p_[11]), p_[12]);
        mp = fmaxf(fmaxf(mp, p_[13]), p_[14]);
        mp = fmaxf(mp, p_[15]);

        // defer-max ballot: 64-lane __all covers every hi-quadrant of every
        // row, so this is exactly the old row-max condition.
        if (!__all(mp - m_run <= 8.f)) {
            float mloc = fmaxf(mp, __shfl_xor(mp, 16));
            mloc = fmaxf(mloc, __shfl_xor(mloc, 32));
            float m_new = fmaxf(m_run, mloc);
            float alpha = EXP2F(m_run - m_new);
            l_run *= alpha;
            #pragma unroll
            for (int dt = 0; dt < 4; ++dt) o[dt] *= alpha;
            m_run = m_new;
        }
        float lsum = 0.f;
        #pragma unroll
        for (int i = 0; i < 16; ++i) {
            float e = EXP2F(p_[i] - m_run);
            p_[i] = e;
            lsum += e;
        }
        l_run += lsum;     // per-lane partial; reduced once in epilogue

        // P -> bf16 fragments via packed convert (identity key bijection)
        bf16x8 pa[2];
        #pragma unroll
        for (int k2 = 0; k2 < 2; ++k2) {
            union { unsigned wd[4]; bf16x8 v; } pu;
            #pragma unroll
            for (int qi = 0; qi < 4; ++qi)
                asm("v_cvt_pk_bf16_f32 %0, %1, %2"
                    : "=v"(pu.wd[qi])
                    : "v"(p_[k2 * 8 + 2 * qi]), "v"(p_[k2 * 8 + 2 * qi + 1]));
            pa[k2] = pu.v;
        }

        // O^T += V^T . P^T ; blocked V: one b128 per (dt,k2)
        __builtin_amdgcn_s_setprio(1);
        #pragma unroll
        for (int dt = 0; dt < 4; ++dt)
            #pragma unroll
            for (int k2 = 0; k2 < 2; ++k2) {
                bf16x8 va = *(const bf16x8*)&Vs[cur][(size_t)((k2 * 4 + hi) * 64 + dt * 16 + ln) * 8];
                o[dt] = MFMA16(va, pa[k2], o[dt]);
            }
        __builtin_amdgcn_s_setprio(0);
    }

    // epilogue: reduce l partials across hi once; lane owns qrow
    float lt = l_run + __shfl_xor(l_run, 16);
    lt += __shfl_xor(lt, 32);
    float inv = 1.f / lt;
    #pragma unroll
    for (int dt = 0; dt < 4; ++dt) {
        ushort4 ov;
        ov.x = f2bf(o[dt][0] * inv);
        ov.y = f2bf(o[dt][1] * inv);
        ov.z = f2bf(o[dt][2] * inv);
        ov.w = f2bf(o[dt][3] * inv);
        *(ushort4*)&ctx[(tok + qrow) * 1024 + h * 64 + dt * 16 + hi * 4] = ov;
    }
}

extern "C" void kernel_launch(void* const* d_in, const int* in_sizes, int n_in,
                              void* d_out, int out_size, void* d_ws, size_t ws_size,
                              hipStream_t stream) {
    const float* hs     = (const float*)d_in[0];   // [2,2048,1024]
    const float* w_attn = (const float*)d_in[1];   // [1024,3072]
    const float* b_attn = (const float*)d_in[2];   // [3072]
    const float* w_proj = (const float*)d_in[3];   // [1024,1024]
    const float* b_proj = (const float*)d_in[4];   // [1024]
    float* out = (float*)d_out;                    // [2,2048,1024] fp32

    char* ws = (char*)d_ws;
    u16* hsb  = (u16*)ws;                          // 8 MB
    u16* waT  = (u16*)(ws + ((size_t)8  << 20));   // 6 MB  [3072][1024]
    u16* wpT  = (u16*)(ws + ((size_t)14 << 20));   // 2 MB  [1024][1024]
    u16* qkvb = (u16*)(ws + ((size_t)16 << 20));   // 24 MB [4096][3072] (V region unused)
    u16* ctxb = (u16*)(ws + ((size_t)40 << 20));   // 8 MB  [4096][1024]
    u16* vtg  = (u16*)(ws + ((size_t)48 << 20));   // 8 MB  blocked V^T

    prep<<<5120, 256, 0, stream>>>(hs, w_attn, w_proj, hsb, waT, wpT);

    gemm_bt<3072, u16, true><<<dim3(32, 24), 256, 0, stream>>>(hsb, waT, b_attn, qkvb, vtg);
    attn_mfma<<<dim3(BB * 16, SS / 64), 256, 0, stream>>>(qkvb, vtg, ctxb);
    gemm_bt<1024, float, false><<<dim3(32, 8), 256, 0, stream>>>(ctxb, wpT, b_proj, out, nullptr);
}